// Round 1
// baseline (182.548 us; speedup 1.0000x reference)
//
#include <hip/hip_runtime.h>

// Problem geometry (fixed by the reference): x[2][4][128][128][128] f32,
// y[2][1][128][128][128] int (harness delivers integer inputs as int32).
constexpr int DD = 128, HH = 128, WW = 128;
constexpr int SPB = DD * HH * WW;        // 2^21 voxels per batch
constexpr int NB = 2, NC = 4;
constexpr int TOTAL = NB * SPB;          // 4,194,304
constexpr float EPSV = 1e-6f;

// ---------------------------------------------------------------------------
// Kernel 1: downcast int32 class map to uint8 (shrinks neighborhood traffic)
// ---------------------------------------------------------------------------
__global__ __launch_bounds__(256) void downcast_y(const int* __restrict__ y,
                                                  unsigned char* __restrict__ yb,
                                                  int n) {
    int i = blockIdx.x * blockDim.x + threadIdx.x;
    if (i < n) yb[i] = (unsigned char)y[i];
}

// ---------------------------------------------------------------------------
// Kernel 2: main fused pass.
// Per (b,c) accumulators packed as acc[b*16 + q*4 + c], q: 0=fp,1=fn,2=sx,3=sy
// ---------------------------------------------------------------------------
template <bool USE_YB>
__global__ __launch_bounds__(256) void lah_main(const float* __restrict__ x,
                                                const unsigned char* __restrict__ yb,
                                                const int* __restrict__ y32,
                                                float* __restrict__ acc) {
    constexpr int VOX_PER_BLOCK = 2048;   // 8 voxels/thread * 256 threads
    const int base = blockIdx.x * VOX_PER_BLOCK;
    const int b = base >> 21;             // constant within a block
    const int boff = b << 21;

    float fp[4] = {0.f, 0.f, 0.f, 0.f};
    float sx[4] = {0.f, 0.f, 0.f, 0.f};
    float fnv[4] = {0.f, 0.f, 0.f, 0.f};
    float syv[4] = {0.f, 0.f, 0.f, 0.f};

    for (int k = 0; k < 8; ++k) {
        const int idx = base + k * 256 + (int)threadIdx.x;
        const int v = idx & (SPB - 1);
        const int z = v >> 14;
        const int yy = (v >> 7) & 127;
        const int xx = v & 127;

        // --- neighborhood class presence + center class ---
        int presence = 0;
#pragma unroll
        for (int dz = -1; dz <= 1; ++dz) {
            const int zz = z + dz;
            if ((unsigned)zz > 127u) continue;
#pragma unroll
            for (int dy = -1; dy <= 1; ++dy) {
                const int yq = yy + dy;
                if ((unsigned)yq > 127u) continue;
#pragma unroll
                for (int dx = -1; dx <= 1; ++dx) {
                    const int xq = xx + dx;
                    if ((unsigned)xq > 127u) continue;
                    const int off = boff + ((zz << 14) | (yq << 7) | xq);
                    const int cls = USE_YB ? (int)yb[off] : y32[off];
                    presence |= (1 << cls);
                }
            }
        }
        const int cc = USE_YB ? (int)yb[boff + v] : y32[boff + v];

        // --- fn: product of (1-x) over neighborhood in plane cc ---
        const float* __restrict__ xp = x + ((long)(b * NC + cc) << 21);
        float P = 1.f;
#pragma unroll
        for (int dz = -1; dz <= 1; ++dz) {
            const int zz = z + dz;
            if ((unsigned)zz > 127u) continue;
#pragma unroll
            for (int dy = -1; dy <= 1; ++dy) {
                const int yq = yy + dy;
                if ((unsigned)yq > 127u) continue;
#pragma unroll
                for (int dx = -1; dx <= 1; ++dx) {
                    const int xq = xx + dx;
                    if ((unsigned)xq > 127u) continue;
                    P *= (1.f - xp[(zz << 14) | (yq << 7) | xq]);
                }
            }
        }
        const float xc = xp[v];
        const float fn_val = (1.f - xc) * (1.f + P);

        // --- fp / sx over all 4 classes; fn/sy scattered branchlessly ---
#pragma unroll
        for (int c = 0; c < 4; ++c) {
            const float xv = x[((long)(b * NC + c) << 21) + v];
            sx[c] += xv;
            const float mult = (presence >> c & 1) ? 1.f : 2.f;
            fp[c] += (cc != c) ? xv * mult : 0.f;
            fnv[c] += (cc == c) ? fn_val : 0.f;
            syv[c] += (cc == c) ? 1.f : 0.f;
        }
    }

    // --- block reduction: 16 scalars ---
    float r[16];
#pragma unroll
    for (int c = 0; c < 4; ++c) {
        r[c] = fp[c];
        r[4 + c] = fnv[c];
        r[8 + c] = sx[c];
        r[12 + c] = syv[c];
    }

    __shared__ float s[16];
#pragma unroll
    for (int i = 0; i < 16; ++i) {
        float vv = r[i];
#pragma unroll
        for (int off = 32; off >= 1; off >>= 1) vv += __shfl_down(vv, off);
        r[i] = vv;
    }
    if (threadIdx.x < 16) s[threadIdx.x] = 0.f;
    __syncthreads();
    if ((threadIdx.x & 63) == 0) {
#pragma unroll
        for (int i = 0; i < 16; ++i) atomicAdd(&s[i], r[i]);
    }
    __syncthreads();
    if (threadIdx.x < 16) atomicAdd(&acc[b * 16 + threadIdx.x], s[threadIdx.x]);
}

// ---------------------------------------------------------------------------
// Kernel 3: finalize scalar loss
// ---------------------------------------------------------------------------
__global__ void lah_finalize(const float* __restrict__ acc, float* __restrict__ out) {
    float loss = 0.f;
#pragma unroll
    for (int b = 0; b < 2; ++b) {
#pragma unroll
        for (int c = 1; c < 4; ++c) {
            const float fp = acc[b * 16 + 0 + c];
            const float fn = acc[b * 16 + 4 + c];
            const float sx = acc[b * 16 + 8 + c];
            const float sy = acc[b * 16 + 12 + c];
            const float a = fp / (sx + EPSV);
            const float bb = fn / (sy + EPSV);
            loss += fmaxf(a, bb);
        }
    }
    out[0] = loss / 6.f;
}

extern "C" void kernel_launch(void* const* d_in, const int* in_sizes, int n_in,
                              void* d_out, int out_size, void* d_ws, size_t ws_size,
                              hipStream_t stream) {
    const float* x = (const float*)d_in[0];
    const int* y32 = (const int*)d_in[1];
    float* out = (float*)d_out;

    float* acc = (float*)d_ws;                       // 32 floats
    unsigned char* yb = (unsigned char*)d_ws + 256;  // TOTAL bytes

    const bool use_yb = ws_size >= (size_t)256 + (size_t)TOTAL;

    hipMemsetAsync(d_ws, 0, 32 * sizeof(float), stream);

    if (use_yb) {
        downcast_y<<<TOTAL / 256, 256, 0, stream>>>(y32, yb, TOTAL);
        lah_main<true><<<TOTAL / 2048, 256, 0, stream>>>(x, yb, nullptr, acc);
    } else {
        lah_main<false><<<TOTAL / 2048, 256, 0, stream>>>(x, nullptr, y32, acc);
    }
    lah_finalize<<<1, 1, 0, stream>>>(acc, out);
}

// Round 2
// 76.800 us; speedup vs baseline: 2.3769x; 2.3769x over previous
//
#include <hip/hip_runtime.h>

// x[2][4][128][128][128] f32, y[2][1][128][128][128] int32
constexpr int SPB = 1 << 21;          // voxels per batch (128^3)
constexpr float EPSV = 1e-6f;
constexpr int ZSEG = 8;               // z-slices per wave
constexpr int NSEG = 128 / ZSEG;      // 16 segments
constexpr int NWAVE = 2 * NSEG * 128; // 4096 waves
constexpr int NBLK = NWAVE / 4;       // 1024 blocks of 4 waves

struct Slice {
    float ypx[4], ypy[4];  // y-direction product of (1-x), per plane, x0/x0+1
    float cxx[4], cxy[4];  // raw center-row x values per plane
    int yor;               // presence OR over 3 rows: bits0-3 -> x0, bits8-11 -> x0+1
    int c0, c1;            // center classes at x0, x0+1
};

__device__ __forceinline__ Slice load_slice(const float* __restrict__ xb,
                                            const int* __restrict__ yb,
                                            int s, int rbase0, bool ym1, bool yp1) {
    Slice r;
    const int rb = (s << 14) | rbase0;

    int2 vm = ym1 ? *(const int2*)(yb + rb - 128) : make_int2(0, 0);
    int2 vc = *(const int2*)(yb + rb);
    int2 vp = yp1 ? *(const int2*)(yb + rb + 128) : make_int2(0, 0);
    const int mm = ym1 ? ((1 << vm.x) | (1 << vm.y) << 8) : 0;
    const int mc = (1 << vc.x) | (1 << vc.y) << 8;
    const int mp = yp1 ? ((1 << vp.x) | (1 << vp.y) << 8) : 0;
    r.yor = mm | mc | mp;
    r.c0 = vc.x;
    r.c1 = vc.y;

#pragma unroll
    for (int c = 0; c < 4; ++c) {
        const float* p = xb + (c << 21) + rb;
        float2 am = ym1 ? *(const float2*)(p - 128) : make_float2(0.f, 0.f);
        float2 ac = *(const float2*)(p);
        float2 ap = yp1 ? *(const float2*)(p + 128) : make_float2(0.f, 0.f);
        r.cxx[c] = ac.x;
        r.cxy[c] = ac.y;
        r.ypx[c] = (1.f - am.x) * (1.f - ac.x) * (1.f - ap.x);
        r.ypy[c] = (1.f - am.y) * (1.f - ac.y) * (1.f - ap.y);
    }
    return r;
}

__device__ __forceinline__ Slice ones_slice() {
    Slice r;
#pragma unroll
    for (int c = 0; c < 4; ++c) {
        r.ypx[c] = 1.f; r.ypy[c] = 1.f; r.cxx[c] = 0.f; r.cxy[c] = 0.f;
    }
    r.yor = 0; r.c0 = -1; r.c1 = -1;
    return r;
}

__global__ __launch_bounds__(256) void lah_stencil(const float* __restrict__ x,
                                                   const int* __restrict__ y32,
                                                   float* __restrict__ acc) {
    const int wid = (blockIdx.x << 2) | (threadIdx.x >> 6);
    const int lane = threadIdx.x & 63;
    const int b = wid >> 11;
    const int rem = wid & 2047;
    const int zs = rem >> 7;
    const int yy = rem & 127;
    const int x0 = lane << 1;
    const int z0 = zs * ZSEG;
    const bool ym1 = yy > 0, yp1v = yy < 127;
    const int rbase0 = (yy << 7) | x0;

    const float* __restrict__ xb = x + ((long)b << 23);
    const int* __restrict__ yb = y32 + ((long)b << 21);

    float fp[4] = {0.f, 0.f, 0.f, 0.f};
    float fnv[4] = {0.f, 0.f, 0.f, 0.f};
    float sx[4] = {0.f, 0.f, 0.f, 0.f};
    float sy[4] = {0.f, 0.f, 0.f, 0.f};

    Slice s0 = (z0 > 0) ? load_slice(xb, yb, z0 - 1, rbase0, ym1, yp1v) : ones_slice();
    Slice s1 = load_slice(xb, yb, z0, rbase0, ym1, yp1v);

#pragma unroll
    for (int dz = 0; dz < ZSEG; ++dz) {
        const int z = z0 + dz;
        Slice s2 = (z + 1 < 128) ? load_slice(xb, yb, z + 1, rbase0, ym1, yp1v)
                                 : ones_slice();

        // presence across z, then across x via shuffles
        const int zor = s0.yor | s1.yor | s2.yor;
        int orL = __shfl_up(zor, 1);
        if (lane == 0) orL = 0;
        int orR = __shfl_down(zor, 1);
        if (lane == 63) orR = 0;
        const int pres0 = (zor | (zor >> 8) | (orL >> 8)) & 15;
        const int pres1 = (zor | (zor >> 8) | orR) & 15;
        const int cc0 = s1.c0, cc1 = s1.c1;

#pragma unroll
        for (int c = 0; c < 4; ++c) {
            const float zpx = s0.ypx[c] * s1.ypx[c] * s2.ypx[c];
            const float zpy = s0.ypy[c] * s1.ypy[c] * s2.ypy[c];
            float zpL = __shfl_up(zpy, 1);
            if (lane == 0) zpL = 1.f;
            float zpR = __shfl_down(zpx, 1);
            if (lane == 63) zpR = 1.f;
            const float P0 = zpL * zpx * zpy;
            const float P1 = zpx * zpy * zpR;

            const float xv0 = s1.cxx[c], xv1 = s1.cxy[c];
            sx[c] += xv0 + xv1;
            const float m0 = (pres0 >> c & 1) ? 1.f : 2.f;
            const float m1 = (pres1 >> c & 1) ? 1.f : 2.f;
            fp[c] += (cc0 != c) ? xv0 * m0 : 0.f;
            fp[c] += (cc1 != c) ? xv1 * m1 : 0.f;
            fnv[c] += (cc0 == c) ? (1.f - xv0) * (1.f + P0) : 0.f;
            fnv[c] += (cc1 == c) ? (1.f - xv1) * (1.f + P1) : 0.f;
            sy[c] += (cc0 == c) ? 1.f : 0.f;
            sy[c] += (cc1 == c) ? 1.f : 0.f;
        }

        s0 = s1;
        s1 = s2;
    }

    // ---- block reduction of 16 scalars, then global atomics ----
    float r[16];
#pragma unroll
    for (int c = 0; c < 4; ++c) {
        r[c] = fp[c];
        r[4 + c] = fnv[c];
        r[8 + c] = sx[c];
        r[12 + c] = sy[c];
    }
    __shared__ float s[16];
#pragma unroll
    for (int i = 0; i < 16; ++i) {
        float vv = r[i];
#pragma unroll
        for (int off = 32; off >= 1; off >>= 1) vv += __shfl_down(vv, off);
        r[i] = vv;
    }
    if (threadIdx.x < 16) s[threadIdx.x] = 0.f;
    __syncthreads();
    if ((threadIdx.x & 63) == 0) {
#pragma unroll
        for (int i = 0; i < 16; ++i) atomicAdd(&s[i], r[i]);
    }
    __syncthreads();
    if (threadIdx.x < 16) atomicAdd(&acc[b * 16 + threadIdx.x], s[threadIdx.x]);
}

__global__ void lah_finalize(const float* __restrict__ acc, float* __restrict__ out) {
    float loss = 0.f;
#pragma unroll
    for (int b = 0; b < 2; ++b) {
#pragma unroll
        for (int c = 1; c < 4; ++c) {
            const float fp = acc[b * 16 + 0 + c];
            const float fn = acc[b * 16 + 4 + c];
            const float sxv = acc[b * 16 + 8 + c];
            const float syv = acc[b * 16 + 12 + c];
            loss += fmaxf(fp / (sxv + EPSV), fn / (syv + EPSV));
        }
    }
    out[0] = loss / 6.f;
}

extern "C" void kernel_launch(void* const* d_in, const int* in_sizes, int n_in,
                              void* d_out, int out_size, void* d_ws, size_t ws_size,
                              hipStream_t stream) {
    const float* x = (const float*)d_in[0];
    const int* y32 = (const int*)d_in[1];
    float* out = (float*)d_out;
    float* acc = (float*)d_ws;  // 32 floats

    hipMemsetAsync(d_ws, 0, 32 * sizeof(float), stream);
    lah_stencil<<<NBLK, 256, 0, stream>>>(x, y32, acc);
    lah_finalize<<<1, 1, 0, stream>>>(acc, out);
}